// Round 1
// 672.196 us; speedup vs baseline: 1.0801x; 1.0801x over previous
//
#include <hip/hip_runtime.h>
#include <math.h>

// ---------------------------------------------------------------------------
// QTable: out = ((q k^T) .* decaymask) v @ wo^T * out_scale, window-truncated.
// B=4, T=2048, V=8192, D=256.  decay^448 ~ 3.5e-10 -> 512-token window exact.
// ---------------------------------------------------------------------------

typedef __bf16 bf16x8 __attribute__((ext_vector_type(8)));
typedef float  f32x4  __attribute__((ext_vector_type(4)));

#define MFMA(a, b, c) __builtin_amdgcn_mfma_f32_16x16x32_bf16((a), (b), (c), 0, 0, 0)

// native cast -> v_cvt_pk_bf16_f32 (RNE), ~4x fewer VALU than manual RNE bit math
__device__ __forceinline__ unsigned short f2bf(float f) {
    __bf16 h = (__bf16)f;
    return __builtin_bit_cast(unsigned short, h);
}

// async 16B/lane global->LDS copy; lds offset must be wave-uniform (lane adds lane*16)
__device__ __forceinline__ void gl_lds16(const void* g, unsigned lds_byte_off,
                                         unsigned short* lds_base) {
    __builtin_amdgcn_global_load_lds(
        (const __attribute__((address_space(1))) void*)g,
        (__attribute__((address_space(3))) void*)((char*)lds_base + lds_byte_off),
        16, 0, 0);
}

// ---------------------------------------------------------------------------
// K1: cast wq,wk,wv -> wqkvb (768x8192 bf16, concat) and wo -> wob (8192x256)
// ---------------------------------------------------------------------------
__global__ __launch_bounds__(256) void cast_w_kernel(
    const float* __restrict__ wq, const float* __restrict__ wk,
    const float* __restrict__ wv, const float* __restrict__ wo,
    unsigned short* __restrict__ wqkvb, unsigned short* __restrict__ wob) {
    size_t i4 = (size_t)blockIdx.x * 256 + threadIdx.x;  // 2,097,152 total
    size_t e = i4 << 2;
    const float* src;
    unsigned short* dst;
    size_t off;
    if (e < 2097152)      { src = wq; off = e;           dst = wqkvb + e; }
    else if (e < 4194304) { src = wk; off = e - 2097152; dst = wqkvb + e; }
    else if (e < 6291456) { src = wv; off = e - 4194304; dst = wqkvb + e; }
    else                  { src = wo; off = e - 6291456; dst = wob + (e - 6291456); }
    float4 f = *(const float4*)(src + off);
    ushort4 u;
    u.x = f2bf(f.x); u.y = f2bf(f.y); u.z = f2bf(f.z); u.w = f2bf(f.w);
    *(ushort4*)dst = u;
}

// ---------------------------------------------------------------------------
// K2: QKV GEMM.  A = x (f32, 8192x8192), B = wqkvb (bf16, 768x8192, B^T form).
// v2: tile 64x128 (was 128x128) -> grid 768 linear = 3 blocks/CU resident
//     (was 384 = 1.4/CU, OccupancyPercent 17%).  XCD-swizzled linear grid so
//     the 6 blocks sharing each 64-row A slice co-reside on one XCD L2.
//     T2 XOR-swizzle (byte ^= (row&7)<<4) on both LDS tiles kills the 16-way
//     ds_read_b128 bank conflict (SQ_LDS_BANK_CONFLICT was 3.8e7/dispatch):
//     A staged via swizzled ds_write (both-sides), B staged via gl_lds16 with
//     pre-swizzled GLOBAL source + linear LDS dest (rule #21).
// C (bf16): cols [0,256)->q, [256,512)->k, [512,768)->v stored TRANSPOSED as
// vT[b][d][t] so the attention PV MFMA can read B-frags contiguously.
// ---------------------------------------------------------------------------
__global__ __launch_bounds__(256) void qkv_gemm_kernel(
    const float* __restrict__ x, const unsigned short* __restrict__ wb,
    unsigned short* __restrict__ qws, unsigned short* __restrict__ kws,
    unsigned short* __restrict__ vtws) {
    __shared__ unsigned short As[64 * 64];    // 8 KB bf16, XOR-swizzled
    __shared__ unsigned short Bs[128 * 64];   // 16 KB bf16, XOR-swizzled
    const int tid = threadIdx.x;
    // bijective XCD swizzle: nwg=768, 768%8==0, 96 contiguous wgs per XCD
    const int wg  = blockIdx.x;
    const int wgs = (wg & 7) * 96 + (wg >> 3);
    const int bx = wgs % 6, by = wgs / 6;     // bx fastest: A-sharers contiguous
    const int n0 = bx * 128;
    const int m0 = by * 64;
    const int lane = tid & 63, wv = tid >> 6;
    const int lid = lane & 15, quad = lane >> 4;
    const int wm = wv >> 1, wn = wv & 1;      // wave -> 32x64 sub-tile

    f32x4 acc[2][4];
#pragma unroll
    for (int i = 0; i < 2; i++)
#pragma unroll
        for (int j = 0; j < 4; j++) acc[i][j] = (f32x4)0.f;

    for (int kc = 0; kc < 8192; kc += 64) {
        // A: f32 global -> native cvt -> bf16 ds_write at XOR-swizzled address
#pragma unroll
        for (int r = 0; r < 4; r++) {
            int chunk = r * 256 + tid;            // [0,1024)
            int row = chunk >> 4, c4 = (chunk & 15) << 2;
            float4 f = *(const float4*)(x + (size_t)(m0 + row) * 8192 + kc + c4);
            ushort4 u;
            u.x = f2bf(f.x); u.y = f2bf(f.y); u.z = f2bf(f.z); u.w = f2bf(f.w);
            unsigned boff = (unsigned)(row * 128) + (((unsigned)(c4 * 2)) ^ ((row & 7) << 4));
            *(ushort4*)((char*)As + boff) = u;
        }
        // B: async 16B/lane, pre-swizzled global source (LDS dest linear)
#pragma unroll
        for (int r = 0; r < 4; r++) {
            int chunk = r * 256 + tid;            // [0,1024)
            int row = chunk >> 3, sp = chunk & 7;
            int c8 = (sp ^ (row & 7)) << 3;
            gl_lds16(wb + (size_t)(n0 + row) * 8192 + kc + c8,
                     (unsigned)(r * 256 + (wv << 6)) * 16, Bs);
        }
        __syncthreads();
#pragma unroll
        for (int kk = 0; kk < 2; kk++) {
            bf16x8 a[2], b[4];
#pragma unroll
            for (int f = 0; f < 2; f++) {
                int row = wm * 32 + f * 16 + lid;
                unsigned boff = (unsigned)(row * 128) +
                                (((unsigned)(kk * 64 + quad * 16)) ^ ((row & 7) << 4));
                a[f] = *(const bf16x8*)((const char*)As + boff);
            }
#pragma unroll
            for (int f = 0; f < 4; f++) {
                int row = wn * 64 + f * 16 + lid;
                unsigned boff = (unsigned)(row * 128) +
                                (((unsigned)(kk * 64 + quad * 16)) ^ ((row & 7) << 4));
                b[f] = *(const bf16x8*)((const char*)Bs + boff);
            }
#pragma unroll
            for (int i = 0; i < 2; i++)
#pragma unroll
                for (int j = 0; j < 4; j++) acc[i][j] = MFMA(a[i], b[j], acc[i][j]);
        }
        __syncthreads();
    }

    if (n0 < 512) {  // q or k: row-major (m x 256) bf16
        unsigned short* dst = (n0 < 256) ? qws : kws;
        const int nb = n0 & 255;
#pragma unroll
        for (int i = 0; i < 2; i++) {
            int row = m0 + wm * 32 + i * 16 + quad * 4;
#pragma unroll
            for (int j = 0; j < 4; j++) {
                int col = nb + wn * 64 + j * 16 + lid;
#pragma unroll
                for (int r = 0; r < 4; r++)
                    dst[(size_t)(row + r) * 256 + col] = f2bf(acc[i][j][r]);
            }
        }
    } else {  // v: store transposed vT[b][d][t]; 4 acc regs = 4 consecutive t
#pragma unroll
        for (int i = 0; i < 2; i++) {
            int row = m0 + wm * 32 + i * 16 + quad * 4;  // global m = b*2048+t
            int bb = row >> 11, t = row & 2047;
#pragma unroll
            for (int j = 0; j < 4; j++) {
                int d = (n0 - 512) + wn * 64 + j * 16 + lid;
                ushort4 u;
                u.x = f2bf(acc[i][j][0]); u.y = f2bf(acc[i][j][1]);
                u.z = f2bf(acc[i][j][2]); u.w = f2bf(acc[i][j][3]);
                *(ushort4*)(&vtws[(((size_t)(bb * 256 + d)) << 11) + t]) = u;
            }
        }
    }
}

// ---------------------------------------------------------------------------
// K3: windowed attention. Grid (dh=2, qt=32, b=4), 256 threads.
// Per block: 64 q-rows x 128 d-cols of retrieved; 4 key-tiles of 128 (window 512).
// Phase A: S(64x128) = Q Ktile^T (K=256).  Weight in f32, ->bf16 LDS.
// Phase B: R += S Vtile (K=128) using vT.
// ---------------------------------------------------------------------------
__global__ __launch_bounds__(256) void attn_kernel(
    const unsigned short* __restrict__ qws, const unsigned short* __restrict__ kws,
    const unsigned short* __restrict__ vtws, unsigned short* __restrict__ retws,
    const float* __restrict__ decay_logit) {
    __shared__ unsigned short qs[64 * 256];   // 32 KB
    __shared__ unsigned short kv[128 * 64];   // 16 KB (ks in phase A, vs in phase B)
    __shared__ unsigned short ss[64 * 128];   // 16 KB weighted scores bf16
    const int tid = threadIdx.x;
    const int dh = blockIdx.x;        // d half
    const int qt = blockIdx.y;        // q tile (64 rows)
    const int b  = blockIdx.z;
    const int t0 = qt * 64;
    const int lane = tid & 63, wv = tid >> 6;
    const int lid = lane & 15, quad = lane >> 4;
    const int wm = wv >> 1, wn = wv & 1;
    const size_t bq0 = (size_t)b * 2048;

    const float dl = decay_logit[0];
    const float decay = 1.f / (1.f + expf(-dl));
    const float l2d = log2f(decay);

    // stage Q tile (64 x 256)
#pragma unroll
    for (int r = 0; r < 8; r++) {
        int chunk = r * 256 + tid;            // [0,2048)
        int row = chunk >> 5, c8 = (chunk & 31) << 3;
        gl_lds16(qws + (bq0 + t0 + row) * 256 + c8,
                 (unsigned)(r * 256 + (wv << 6)) * 16, qs);
    }

    f32x4 racc[2][4];
#pragma unroll
    for (int i = 0; i < 2; i++)
#pragma unroll
        for (int j = 0; j < 4; j++) racc[i][j] = (f32x4)0.f;

    for (int kt = 0; kt < 4; kt++) {
        const int s0 = t0 + kt * 128;
        if (s0 >= 2048) break;
        f32x4 sacc[2][4];
#pragma unroll
        for (int i = 0; i < 2; i++)
#pragma unroll
            for (int j = 0; j < 4; j++) sacc[i][j] = (f32x4)0.f;

        // ---- Phase A: S = Q Ktile^T over D=256 (BK=64) ----
#pragma unroll
        for (int kc = 0; kc < 4; kc++) {
#pragma unroll
            for (int r = 0; r < 4; r++) {
                int chunk = r * 256 + tid;    // [0,1024)
                int row = chunk >> 3, c8 = (chunk & 7) << 3;
                int srow = s0 + row; if (srow > 2047) srow = 2047;  // masked later
                gl_lds16(kws + (bq0 + srow) * 256 + kc * 64 + c8,
                         (unsigned)(r * 256 + (wv << 6)) * 16, kv);
            }
            __syncthreads();
#pragma unroll
            for (int kk = 0; kk < 2; kk++) {
                bf16x8 a[2], bb[4];
#pragma unroll
                for (int f = 0; f < 2; f++)
                    a[f] = *(const bf16x8*)(&qs[(wm * 32 + f * 16 + lid) * 256 + kc * 64 + kk * 32 + quad * 8]);
#pragma unroll
                for (int f = 0; f < 4; f++)
                    bb[f] = *(const bf16x8*)(&kv[(wn * 64 + f * 16 + lid) * 64 + kk * 32 + quad * 8]);
#pragma unroll
                for (int i = 0; i < 2; i++)
#pragma unroll
                    for (int j = 0; j < 4; j++) sacc[i][j] = MFMA(a[i], bb[j], sacc[i][j]);
            }
            __syncthreads();
        }

        // ---- decay weighting (f32) -> bf16 into ss ----
#pragma unroll
        for (int i = 0; i < 2; i++) {
            int trow = wm * 32 + i * 16 + quad * 4;   // local t
#pragma unroll
            for (int j = 0; j < 4; j++) {
                int scol = wn * 64 + j * 16 + lid;    // local s
                int s = s0 + scol;
#pragma unroll
                for (int r = 0; r < 4; r++) {
                    int t = t0 + trow + r;
                    int f = s - t;
                    float w = 0.f;
                    if (f > 0 && s < 2048) w = exp2f((float)(f - 1) * l2d);
                    ss[(trow + r) * 128 + scol] = f2bf(sacc[i][j][r] * w);
                }
            }
        }
        __syncthreads();

        // ---- Phase B: R += S Vtile over s (K=128, BK=64) ----
#pragma unroll
        for (int kc = 0; kc < 2; kc++) {
#pragma unroll
            for (int r = 0; r < 4; r++) {
                int chunk = r * 256 + tid;    // [0,1024)
                int row = chunk >> 3, c8 = (chunk & 7) << 3;
                int col = s0 + kc * 64 + c8; if (col > 2040) col = 2040;  // ss==0 there
                gl_lds16(vtws + ((size_t)(b * 256 + dh * 128 + row) << 11) + col,
                         (unsigned)(r * 256 + (wv << 6)) * 16, kv);
            }
            __syncthreads();
#pragma unroll
            for (int kk = 0; kk < 2; kk++) {
                bf16x8 a[2], bb[4];
#pragma unroll
                for (int f = 0; f < 2; f++)
                    a[f] = *(const bf16x8*)(&ss[(wm * 32 + f * 16 + lid) * 128 + kc * 64 + kk * 32 + quad * 8]);
#pragma unroll
                for (int f = 0; f < 4; f++)
                    bb[f] = *(const bf16x8*)(&kv[(wn * 64 + f * 16 + lid) * 64 + kk * 32 + quad * 8]);
#pragma unroll
                for (int i = 0; i < 2; i++)
#pragma unroll
                    for (int j = 0; j < 4; j++) racc[i][j] = MFMA(a[i], bb[j], racc[i][j]);
            }
            __syncthreads();
        }
    }

    // epilogue: retrieved bf16 (b*2048+t, 256)
#pragma unroll
    for (int i = 0; i < 2; i++) {
#pragma unroll
        for (int j = 0; j < 4; j++) {
            int d = dh * 128 + wn * 64 + j * 16 + lid;
#pragma unroll
            for (int r = 0; r < 4; r++) {
                int t = t0 + wm * 32 + i * 16 + quad * 4 + r;
                retws[(bq0 + t) * 256 + d] = f2bf(racc[i][j][r]);
            }
        }
    }
}

// ---------------------------------------------------------------------------
// K4: output GEMM. A = retws (8192x256 bf16), B = wob (8192x256 bf16, B^T form),
// C = out f32 scaled. Tile 128x128, BK=64 (4 iters). Grid (64,64).
// ---------------------------------------------------------------------------
__global__ __launch_bounds__(256) void out_gemm_kernel(
    const unsigned short* __restrict__ retws, const unsigned short* __restrict__ wob,
    float* __restrict__ out, const float* __restrict__ out_scale) {
    __shared__ unsigned short As[128 * 64];
    __shared__ unsigned short Bs[128 * 64];
    const int tid = threadIdx.x;
    const int n0 = blockIdx.x * 128;
    const int m0 = blockIdx.y * 128;
    const int lane = tid & 63, wv = tid >> 6;
    const int lid = lane & 15, quad = lane >> 4;
    const int wm = wv >> 1, wn = wv & 1;

    f32x4 acc[4][4];
#pragma unroll
    for (int i = 0; i < 4; i++)
#pragma unroll
        for (int j = 0; j < 4; j++) acc[i][j] = (f32x4)0.f;

#pragma unroll
    for (int kc = 0; kc < 256; kc += 64) {
#pragma unroll
        for (int r = 0; r < 4; r++) {
            int chunk = r * 256 + tid;
            int row = chunk >> 3, c8 = (chunk & 7) << 3;
            gl_lds16(retws + (size_t)(m0 + row) * 256 + kc + c8,
                     (unsigned)(r * 256 + (wv << 6)) * 16, As);
        }
#pragma unroll
        for (int r = 0; r < 4; r++) {
            int chunk = r * 256 + tid;
            int row = chunk >> 3, c8 = (chunk & 7) << 3;
            gl_lds16(wob + (size_t)(n0 + row) * 256 + kc + c8,
                     (unsigned)(r * 256 + (wv << 6)) * 16, Bs);
        }
        __syncthreads();
#pragma unroll
        for (int kk = 0; kk < 2; kk++) {
            bf16x8 a[4], b[4];
#pragma unroll
            for (int f = 0; f < 4; f++)
                a[f] = *(const bf16x8*)(&As[(wm * 64 + f * 16 + lid) * 64 + kk * 32 + quad * 8]);
#pragma unroll
            for (int f = 0; f < 4; f++)
                b[f] = *(const bf16x8*)(&Bs[(wn * 64 + f * 16 + lid) * 64 + kk * 32 + quad * 8]);
#pragma unroll
            for (int i = 0; i < 4; i++)
#pragma unroll
                for (int j = 0; j < 4; j++) acc[i][j] = MFMA(a[i], b[j], acc[i][j]);
        }
        __syncthreads();
    }

    const float os = out_scale[0];
#pragma unroll
    for (int i = 0; i < 4; i++) {
        int row = m0 + wm * 64 + i * 16 + quad * 4;
#pragma unroll
        for (int j = 0; j < 4; j++) {
            int col = n0 + wn * 64 + j * 16 + lid;
#pragma unroll
            for (int r = 0; r < 4; r++)
                out[(size_t)(row + r) * 8192 + col] = acc[i][j][r] * os;
        }
    }
}

// ---------------------------------------------------------------------------
extern "C" void kernel_launch(void* const* d_in, const int* in_sizes, int n_in,
                              void* d_out, int out_size, void* d_ws, size_t ws_size,
                              hipStream_t stream) {
    const float* x   = (const float*)d_in[0];
    const float* wq  = (const float*)d_in[1];
    const float* wk  = (const float*)d_in[2];
    const float* wv  = (const float*)d_in[3];
    const float* wo  = (const float*)d_in[4];
    const float* dl  = (const float*)d_in[5];
    const float* osc = (const float*)d_in[6];
    float* out = (float*)d_out;

    char* ws = (char*)d_ws;
    unsigned short* wqkvb = (unsigned short*)(ws);              // 768*8192*2  = 12,582,912
    unsigned short* wob   = (unsigned short*)(ws + 12582912);   // 8192*256*2  =  4,194,304
    unsigned short* qws   = (unsigned short*)(ws + 16777216);   //  4,194,304
    unsigned short* kws   = (unsigned short*)(ws + 20971520);   //  4,194,304
    unsigned short* vtws  = (unsigned short*)(ws + 25165824);   //  4,194,304 (vT[b][d][t])
    unsigned short* retws = (unsigned short*)(ws + 29360128);   //  4,194,304  -> total 32 MB

    hipLaunchKernelGGL(cast_w_kernel, dim3(8192), dim3(256), 0, stream,
                       wq, wk, wv, wo, wqkvb, wob);
    hipLaunchKernelGGL(qkv_gemm_kernel, dim3(768), dim3(256), 0, stream,
                       x, wqkvb, qws, kws, vtws);
    hipLaunchKernelGGL(attn_kernel, dim3(2, 32, 4), dim3(256), 0, stream,
                       qws, kws, vtws, retws, dl);
    hipLaunchKernelGGL(out_gemm_kernel, dim3(64, 64), dim3(256), 0, stream,
                       retws, wob, out, osc);
}